// Round 4
// baseline (129.604 us; speedup 1.0000x reference)
//
#include <hip/hip_runtime.h>
#include <hip/hip_bf16.h>
#include <hip/hip_fp8.h>

#define B_ 8192
#define D_ 256
#define EPS_ 1e-6f
#define MARGIN_ 1.0f
#define NT_ 64                               // 128-row tiles
#define NTILES_ (NT_ * (NT_ + 1) / 2)        // 2080
#define GRID_ 520                            // 4 tiles per block
#define CEPS_ ((float)D_ * EPS_ * EPS_)

typedef float floatx4 __attribute__((ext_vector_type(4)));
typedef __bf16 bf16x4 __attribute__((ext_vector_type(4)));

typedef __attribute__((address_space(3))) unsigned int lds_uint_t;
typedef __attribute__((address_space(1))) const unsigned int g_uint_t;

__device__ __forceinline__ void g2l16(const unsigned char* g, unsigned char* l) {
    __builtin_amdgcn_global_load_lds((g_uint_t*)g, (lds_uint_t*)l, 16, 0, 0);
}

// ws layout: [0, 2MB) fp8 matrix; float region after 4 MB (offsets in floats)
#define XBF_BYTES (B_ * D_ * 2)
#define OFF_P      0
#define OFF_Q      8192
#define OFF_TP0    16384
#define OFF_TP1    81920
#define OFF_PPP    147456
#define OFF_QQP    147968
#define OFF_CP     148480
#define OFF_PMINP  148736
#define OFF_QMINP  148992
#define OFF_ACC    149248

__device__ __forceinline__ int trif(int t) { return (t * (129 - t)) / 2; }
__device__ __forceinline__ int decode_ti(int t) {
    int ti = (int)((129.0f - sqrtf(fmaxf(16641.0f - 8.0f * (float)t, 0.0f))) * 0.5f);
    ti = max(0, min(63, ti));
    while (trif(ti + 1) <= t) ++ti;
    while (trif(ti) > t) --ti;
    return ti;
}

// ---------------- prep: 256 blocks x 32 rows; p/q, col-sums, fp8 cast ----------------
__global__ __launch_bounds__(256) void prep_kernel(
    const float* __restrict__ x, const int* __restrict__ label,
    unsigned char* __restrict__ xq, float* __restrict__ fws) {
    float* p = fws + OFF_P;   float* q = fws + OFF_Q;
    float* Tp0 = fws + OFF_TP0; float* Tp1 = fws + OFF_TP1;
    float* PpP = fws + OFF_PPP; float* QqP = fws + OFF_QQP;
    float* CpP = fws + OFF_CP;
    float* pminP = fws + OFF_PMINP; float* qminP = fws + OFF_QMINP;
    float* acc = fws + OFF_ACC;

    __shared__ int lab_s[32];
    __shared__ float spl[32], sql[32];
    __shared__ float colbuf0[4][256], colbuf1[4][256];

    const int blk = blockIdx.x;
    const int r0 = blk * 32;
    const int tid = threadIdx.x, w = tid >> 6, lane = tid & 63;

    if (tid < 32) lab_s[tid] = label[r0 + tid];
    __syncthreads();

    floatx4 t0 = (floatx4)0.0f, t1 = (floatx4)0.0f;
    #pragma unroll
    for (int i = 0; i < 8; ++i) {
        const int rloc = w * 8 + i;
        const int row = r0 + rloc;
        const floatx4 v = *(const floatx4*)(x + (size_t)row * D_ + lane * 4);
        float sq = v[0]*v[0] + v[1]*v[1] + v[2]*v[2] + v[3]*v[3];
        float rs = v[0] + v[1] + v[2] + v[3];
        #pragma unroll
        for (int off = 32; off; off >>= 1) {
            sq += __shfl_down(sq, off);
            rs += __shfl_down(rs, off);
        }
        if (lane == 0) {
            const float pv = sq + 2.0f * EPS_ * rs;
            const float qv = sq - 2.0f * EPS_ * rs;
            p[row] = pv; q[row] = qv; spl[rloc] = pv; sql[rloc] = qv;
        }
        if (lab_s[rloc]) t1 += v; else t0 += v;   // wave-uniform branch
        // fp8 e4m3 cast, 4 bytes packed
        __hip_fp8_e4m3 c0(v[0]), c1(v[1]), c2(v[2]), c3(v[3]);
        const unsigned int u = (unsigned int)c0.__x | ((unsigned int)c1.__x << 8)
                             | ((unsigned int)c2.__x << 16) | ((unsigned int)c3.__x << 24);
        *(unsigned int*)(xq + (size_t)row * D_ + lane * 4) = u;
    }
    *(floatx4*)&colbuf0[w][lane * 4] = t0;
    *(floatx4*)&colbuf1[w][lane * 4] = t1;
    __syncthreads();

    {
        const int c = tid;
        Tp0[blk * 256 + c] = colbuf0[0][c] + colbuf0[1][c] + colbuf0[2][c] + colbuf0[3][c];
        Tp1[blk * 256 + c] = colbuf1[0][c] + colbuf1[1][c] + colbuf1[2][c] + colbuf1[3][c];
    }
    if (tid < 64) {
        const bool va = tid < 32;
        const float pv = va ? spl[tid & 31] : 0.0f;
        const float qv = va ? sql[tid & 31] : 0.0f;
        const int lb = va ? lab_s[tid & 31] : 0;
        float p0 = (va && !lb) ? pv : 0.0f, p1 = (va && lb) ? pv : 0.0f;
        float q0 = (va && !lb) ? qv : 0.0f, q1 = (va && lb) ? qv : 0.0f;
        float c0 = (va && !lb) ? 1.0f : 0.0f;
        float pm = va ? pv : 1e30f, qm = va ? qv : 1e30f;
        #pragma unroll
        for (int off = 32; off; off >>= 1) {
            p0 += __shfl_down(p0, off); p1 += __shfl_down(p1, off);
            q0 += __shfl_down(q0, off); q1 += __shfl_down(q1, off);
            c0 += __shfl_down(c0, off);
            pm = fminf(pm, __shfl_down(pm, off));
            qm = fminf(qm, __shfl_down(qm, off));
        }
        if (tid == 0) {
            PpP[blk * 2 + 0] = p0; PpP[blk * 2 + 1] = p1;
            QqP[blk * 2 + 0] = q0; QqP[blk * 2 + 1] = q1;
            CpP[blk] = c0; pminP[blk] = pm; qminP[blk] = qm;
            if (blk == 0) acc[0] = 0.0f;
        }
    }
}

// ---------------- tile: fp8 gram, 4 tiles/block, tile-grained pipeline ----------------
__global__ __launch_bounds__(256, 2) void tile_kernel(
    const unsigned char* __restrict__ xq, const float* __restrict__ x,
    const int* __restrict__ label, const float* __restrict__ fws,
    float* __restrict__ acc) {
    const float* p = fws + OFF_P;  const float* q = fws + OFF_Q;
    const float* pminP = fws + OFF_PMINP; const float* qminP = fws + OFF_QMINP;

    __shared__ __align__(16) unsigned char As[2][128 * 128];  // [kh][row*128 + swizzled col]
    __shared__ __align__(16) unsigned char Bs[2][128 * 128];

    const int tid = threadIdx.x, wave = tid >> 6, lane = tid & 63;
    const int quad = lane >> 4, r = lane & 15;
    const int wm = wave >> 1, wn = wave & 1;

    // staging: lane L covers row_off = L>>3, phys chunk L&7, logical chunk (L&7)^(L>>3)
    const int rL = lane >> 3;
    const int cc16 = ((lane & 7) ^ rL) * 16;   // source byte offset within 128-B half-row

    // fragment row bases (byte offsets within a half buffer)
    int rbA[4], rbB[4];
    #pragma unroll
    for (int mt = 0; mt < 4; ++mt) rbA[mt] = (wm * 64 + mt * 16 + r) * 128;
    #pragma unroll
    for (int nt = 0; nt < 4; ++nt) rbB[nt] = (wn * 64 + nt * 16 + r) * 128;
    const int q8 = (quad & 1) * 8, qh = quad >> 1, r7 = r & 7;

    floatx4 accv[16];
    #pragma unroll
    for (int t = 0; t < 16; ++t) accv[t] = (floatx4)0.0f;

#define STAGE(i0_, j0_, kh_) do {                                                  \
        const unsigned char* gA_ = xq + (size_t)((i0_) + wave * 32 + rL) * D_ + (kh_) * 128 + cc16; \
        const unsigned char* gB_ = xq + (size_t)((j0_) + wave * 32 + rL) * D_ + (kh_) * 128 + cc16; \
        _Pragma("unroll")                                                          \
        for (int ps = 0; ps < 4; ++ps) {                                           \
            g2l16(gA_ + ps * 8 * D_, &As[kh_][(wave * 32 + ps * 8) * 128]);        \
            g2l16(gB_ + ps * 8 * D_, &Bs[kh_][(wave * 32 + ps * 8) * 128]);        \
        }                                                                          \
    } while (0)

#define COMPUTE(kh_) do {                                                          \
        const unsigned char* Ab_ = As[kh_];                                        \
        const unsigned char* Bb_ = Bs[kh_];                                        \
        _Pragma("unroll")                                                          \
        for (int kb = 0; kb < 4; ++kb) {                                           \
            const int pcb = (((kb * 2 + qh) ^ r7) * 16) + q8;                      \
            long av[4], bv[4];                                                     \
            _Pragma("unroll")                                                      \
            for (int mt = 0; mt < 4; ++mt) av[mt] = *(const long*)(Ab_ + rbA[mt] + pcb); \
            _Pragma("unroll")                                                      \
            for (int nt = 0; nt < 4; ++nt) bv[nt] = *(const long*)(Bb_ + rbB[nt] + pcb); \
            _Pragma("unroll")                                                      \
            for (int mt = 0; mt < 4; ++mt)                                         \
                _Pragma("unroll")                                                  \
                for (int nt = 0; nt < 4; ++nt)                                     \
                    accv[mt * 4 + nt] = __builtin_amdgcn_mfma_f32_16x16x32_fp8_fp8( \
                        av[mt], bv[nt], accv[mt * 4 + nt], 0, 0, 0);               \
        }                                                                          \
    } while (0)

    // tile 0 of this block
    int t_cur = blockIdx.x * 4;
    int ti = decode_ti(t_cur);
    int tj = ti + (t_cur - trif(ti));
    int i0 = ti * 128, j0 = tj * 128;
    int n_i0 = 0, n_j0 = 0, n_ti = 0, n_tj = 0;

    STAGE(i0, j0, 0);

    #pragma unroll 1
    for (int it = 0; it < 4; ++it) {
        __syncthreads();                 // drains stage(kh0) of current tile
        STAGE(i0, j0, 1);
        COMPUTE(0);
        __syncthreads();                 // all waves done reading buf0; drains stage(kh1)
        if (it < 3) {
            const int t_n = blockIdx.x * 4 + it + 1;
            n_ti = decode_ti(t_n);
            n_tj = n_ti + (t_n - trif(n_ti));
            n_i0 = n_ti * 128; n_j0 = n_tj * 128;
            STAGE(n_i0, n_j0, 0);        // prefetch next tile's half0 into buf0
        }
        COMPUTE(1);

        // ---- epilogue for tile (ti, tj) ----
        if (ti != tj) {
            float m = -1e30f;
            #pragma unroll
            for (int t = 0; t < 16; ++t)
                m = fmaxf(m, fmaxf(fmaxf(accv[t][0], accv[t][1]), fmaxf(accv[t][2], accv[t][3])));
            const float pmn = fminf(fminf(pminP[4 * ti], pminP[4 * ti + 1]),
                                    fminf(pminP[4 * ti + 2], pminP[4 * ti + 3]));
            const float qmn = fminf(fminf(qminP[4 * tj], qminP[4 * tj + 1]),
                                    fminf(qminP[4 * tj + 2], qminP[4 * tj + 3]));
            const float thr = (pmn + qmn + CEPS_ - 1.0f) * 0.5f - 16.0f;  // 16 = fp8 slack
            if (__any(m > thr)) {
                // exact slow path from fp32 x (expected never taken)
                float s = 0.0f;
                #pragma unroll
                for (int mt = 0; mt < 4; ++mt)
                    #pragma unroll
                    for (int nt = 0; nt < 4; ++nt)
                        #pragma unroll
                        for (int reg = 0; reg < 4; ++reg) {
                            const int gi = i0 + wm * 64 + mt * 16 + quad * 4 + reg;
                            const int gj = j0 + wn * 64 + nt * 16 + r;
                            const float sq8 = p[gi] + q[gj] + CEPS_ - 2.0f * accv[mt * 4 + nt][reg];
                            if (sq8 < 33.0f && label[gi] != label[gj]) {
                                const float* xi = x + (size_t)gi * D_;
                                const float* xj = x + (size_t)gj * D_;
                                float sq = 0.0f;
                                for (int k = 0; k < D_; ++k) {
                                    const float df = xi[k] - xj[k] + EPS_;
                                    sq += df * df;
                                }
                                if (sq < 1.0f) {
                                    const float d = sqrtf(fmaxf(sq, 1e-12f));
                                    const float h = MARGIN_ - d;
                                    s += h * h;
                                }
                            }
                        }
                #pragma unroll
                for (int off = 32; off; off >>= 1) s += __shfl_down(s, off);
                if (lane == 0) atomicAdd(acc, s);
            }
        } else {
            // diagonal: exact per-pair, strict upper triangle
            float s = 0.0f;
            #pragma unroll
            for (int mt = 0; mt < 4; ++mt)
                #pragma unroll
                for (int nt = 0; nt < 4; ++nt)
                    #pragma unroll
                    for (int reg = 0; reg < 4; ++reg) {
                        const int il = wm * 64 + mt * 16 + quad * 4 + reg;
                        const int jl = wn * 64 + nt * 16 + r;
                        if (il < jl) {
                            const int gi = i0 + il, gj = j0 + jl;
                            const float sq = p[gi] + q[gj] + CEPS_ - 2.0f * accv[mt * 4 + nt][reg];
                            const float d = sqrtf(fmaxf(sq, 1e-12f));
                            float v;
                            if (label[gi] == label[gj]) v = d * d;
                            else { const float h = fmaxf(MARGIN_ - d, 0.0f); v = h * h; }
                            s += v;
                        }
                    }
            #pragma unroll
            for (int off = 32; off; off >>= 1) s += __shfl_down(s, off);
            if (lane == 0) atomicAdd(acc, s);
        }

        // reset accumulators, advance tile
        #pragma unroll
        for (int t = 0; t < 16; ++t) accv[t] = (floatx4)0.0f;
        ti = n_ti; tj = n_tj; i0 = n_i0; j0 = n_j0;
    }
#undef STAGE
#undef COMPUTE
}

// ---------------- finalize: parallel analytic cross-tile same-label sum ----------------
__global__ __launch_bounds__(256) void finalize_kernel(
    const float* __restrict__ fws, float* __restrict__ out) {
    const float* Tp0 = fws + OFF_TP0; const float* Tp1 = fws + OFF_TP1;
    const float* PpP = fws + OFF_PPP; const float* QqP = fws + OFF_QQP;
    const float* CpP = fws + OFF_CP;
    const float* acc = fws + OFF_ACC;

    __shared__ floatx4 s0q[4][64], s1q[4][64], ssq[4][64];
    __shared__ float g2s;
    __shared__ double tP0[64], tP1[64], tQ0[64], tQ1[64], tC0[64];

    const int tid = threadIdx.x;
    const int quad = tid & 63, tq = tid >> 6;

    floatx4 a0 = (floatx4)0.0f, a1 = (floatx4)0.0f, as = (floatx4)0.0f;
    for (int t = tq; t < 64; t += 4) {
        floatx4 T0 = (floatx4)0.0f, T1 = (floatx4)0.0f;
        #pragma unroll
        for (int b4 = 0; b4 < 4; ++b4) {
            const int blk = 4 * t + b4;
            T0 += *(const floatx4*)&Tp0[blk * 256 + quad * 4];
            T1 += *(const floatx4*)&Tp1[blk * 256 + quad * 4];
        }
        a0 += T0; as += T0 * T0;
        a1 += T1; as += T1 * T1;
    }
    s0q[tq][quad] = a0; s1q[tq][quad] = a1; ssq[tq][quad] = as;

    if (tid >= 64 && tid < 128) {
        const int t = tid - 64;
        double P0 = 0, P1 = 0, Q0 = 0, Q1 = 0, C0 = 0;
        #pragma unroll
        for (int b4 = 0; b4 < 4; ++b4) {
            const int blk = 4 * t + b4;
            P0 += PpP[blk * 2]; P1 += PpP[blk * 2 + 1];
            Q0 += QqP[blk * 2]; Q1 += QqP[blk * 2 + 1];
            C0 += CpP[blk];
        }
        tP0[t] = P0; tP1[t] = P1; tQ0[t] = Q0; tQ1[t] = Q1; tC0[t] = C0;
    }
    __syncthreads();

    if (tid < 64) {
        const floatx4 S0 = s0q[0][tid] + s0q[1][tid] + s0q[2][tid] + s0q[3][tid];
        const floatx4 S1 = s1q[0][tid] + s1q[1][tid] + s1q[2][tid] + s1q[3][tid];
        const floatx4 SS = ssq[0][tid] + ssq[1][tid] + ssq[2][tid] + ssq[3][tid];
        float c = S0[0]*S0[0] + S0[1]*S0[1] + S0[2]*S0[2] + S0[3]*S0[3]
                + S1[0]*S1[0] + S1[1]*S1[1] + S1[2]*S1[2] + S1[3]*S1[3]
                - (SS[0] + SS[1] + SS[2] + SS[3]);
        #pragma unroll
        for (int off = 32; off; off >>= 1) c += __shfl_down(c, off);
        if (tid == 0) g2s = c;
    }
    __syncthreads();

    if (tid == 0) {
        double cross = -(double)g2s;
        double sufC0 = 0, sufC1 = 0, sufQ0 = 0, sufQ1 = 0;
        for (int t = 63; t >= 0; --t) {
            const double C0 = tC0[t], C1 = 128.0 - C0;
            cross += tP0[t] * sufC0 + tP1[t] * sufC1 + sufQ0 * C0 + sufQ1 * C1
                   + (double)CEPS_ * (C0 * sufC0 + C1 * sufC1);
            sufC0 += C0; sufC1 += C1; sufQ0 += tQ0[t]; sufQ1 += tQ1[t];
        }
        const double total = cross + (double)acc[0];
        const double cnt = (double)B_ * (double)(B_ - 1) / 2.0 + 1e-6;
        out[0] = (float)(total / cnt);
    }
}

extern "C" void kernel_launch(void* const* d_in, const int* in_sizes, int n_in,
                              void* d_out, int out_size, void* d_ws, size_t ws_size,
                              hipStream_t stream) {
    const float* x = (const float*)d_in[0];
    const int* label = (const int*)d_in[1];
    float* out = (float*)d_out;

    char* ws = (char*)d_ws;
    unsigned char* xq = (unsigned char*)ws;
    float* fws = (float*)(ws + XBF_BYTES);
    float* acc = fws + OFF_ACC;

    prep_kernel<<<B_ / 32, 256, 0, stream>>>(x, label, xq, fws);
    tile_kernel<<<GRID_, 256, 0, stream>>>(xq, x, label, fws, acc);
    finalize_kernel<<<1, 256, 0, stream>>>(fws, out);
}

// Round 5
// 105.224 us; speedup vs baseline: 1.2317x; 1.2317x over previous
//
#include <hip/hip_runtime.h>
#include <hip/hip_bf16.h>
#include <hip/hip_fp8.h>

#define B_ 8192
#define D_ 256
#define EPS_ 1e-6f
#define MARGIN_ 1.0f
#define NT_ 64                               // 128-row tiles
#define NTILES_ (NT_ * (NT_ + 1) / 2)        // 2080
#define CEPS_ ((float)D_ * EPS_ * EPS_)

typedef float floatx4 __attribute__((ext_vector_type(4)));

typedef __attribute__((address_space(3))) unsigned int lds_uint_t;
typedef __attribute__((address_space(1))) const unsigned int g_uint_t;

__device__ __forceinline__ void g2l16(const unsigned char* g, unsigned char* l) {
    __builtin_amdgcn_global_load_lds((g_uint_t*)g, (lds_uint_t*)l, 16, 0, 0);
}

// ws layout: [0, 2MB) fp8 matrix; float region after 4 MB (offsets in floats)
#define XBF_BYTES (B_ * D_ * 2)
#define OFF_P      0
#define OFF_Q      8192
#define OFF_TP0    16384
#define OFF_TP1    81920
#define OFF_PPP    147456
#define OFF_QQP    147968
#define OFF_CP     148480
#define OFF_PMINP  148736
#define OFF_QMINP  148992
#define OFF_ACC    149248

__device__ __forceinline__ int trif(int t) { return (t * (129 - t)) / 2; }
__device__ __forceinline__ int decode_ti(int t) {
    int ti = (int)((129.0f - sqrtf(fmaxf(16641.0f - 8.0f * (float)t, 0.0f))) * 0.5f);
    ti = max(0, min(63, ti));
    while (trif(ti + 1) <= t) ++ti;
    while (trif(ti) > t) --ti;
    return ti;
}

// ---------------- prep: 256 blocks x 32 rows; p/q, col-sums, fp8 cast ----------------
__global__ __launch_bounds__(256) void prep_kernel(
    const float* __restrict__ x, const int* __restrict__ label,
    unsigned char* __restrict__ xq, float* __restrict__ fws) {
    float* p = fws + OFF_P;   float* q = fws + OFF_Q;
    float* Tp0 = fws + OFF_TP0; float* Tp1 = fws + OFF_TP1;
    float* PpP = fws + OFF_PPP; float* QqP = fws + OFF_QQP;
    float* CpP = fws + OFF_CP;
    float* pminP = fws + OFF_PMINP; float* qminP = fws + OFF_QMINP;
    float* acc = fws + OFF_ACC;

    __shared__ int lab_s[32];
    __shared__ float spl[32], sql[32];
    __shared__ float colbuf0[4][256], colbuf1[4][256];

    const int blk = blockIdx.x;
    const int r0 = blk * 32;
    const int tid = threadIdx.x, w = tid >> 6, lane = tid & 63;

    if (tid < 32) lab_s[tid] = label[r0 + tid];
    __syncthreads();

    floatx4 t0 = (floatx4)0.0f, t1 = (floatx4)0.0f;
    #pragma unroll
    for (int i = 0; i < 8; ++i) {
        const int rloc = w * 8 + i;
        const int row = r0 + rloc;
        const floatx4 v = *(const floatx4*)(x + (size_t)row * D_ + lane * 4);
        float sq = v[0]*v[0] + v[1]*v[1] + v[2]*v[2] + v[3]*v[3];
        float rs = v[0] + v[1] + v[2] + v[3];
        #pragma unroll
        for (int off = 32; off; off >>= 1) {
            sq += __shfl_down(sq, off);
            rs += __shfl_down(rs, off);
        }
        if (lane == 0) {
            const float pv = sq + 2.0f * EPS_ * rs;
            const float qv = sq - 2.0f * EPS_ * rs;
            p[row] = pv; q[row] = qv; spl[rloc] = pv; sql[rloc] = qv;
        }
        if (lab_s[rloc]) t1 += v; else t0 += v;   // wave-uniform branch
        __hip_fp8_e4m3 c0(v[0]), c1(v[1]), c2(v[2]), c3(v[3]);
        const unsigned int u = (unsigned int)c0.__x | ((unsigned int)c1.__x << 8)
                             | ((unsigned int)c2.__x << 16) | ((unsigned int)c3.__x << 24);
        *(unsigned int*)(xq + (size_t)row * D_ + lane * 4) = u;
    }
    *(floatx4*)&colbuf0[w][lane * 4] = t0;
    *(floatx4*)&colbuf1[w][lane * 4] = t1;
    __syncthreads();

    {
        const int c = tid;
        Tp0[blk * 256 + c] = colbuf0[0][c] + colbuf0[1][c] + colbuf0[2][c] + colbuf0[3][c];
        Tp1[blk * 256 + c] = colbuf1[0][c] + colbuf1[1][c] + colbuf1[2][c] + colbuf1[3][c];
    }
    if (tid < 64) {
        const bool va = tid < 32;
        const float pv = va ? spl[tid & 31] : 0.0f;
        const float qv = va ? sql[tid & 31] : 0.0f;
        const int lb = va ? lab_s[tid & 31] : 0;
        float p0 = (va && !lb) ? pv : 0.0f, p1 = (va && lb) ? pv : 0.0f;
        float q0 = (va && !lb) ? qv : 0.0f, q1 = (va && lb) ? qv : 0.0f;
        float c0 = (va && !lb) ? 1.0f : 0.0f;
        float pm = va ? pv : 1e30f, qm = va ? qv : 1e30f;
        #pragma unroll
        for (int off = 32; off; off >>= 1) {
            p0 += __shfl_down(p0, off); p1 += __shfl_down(p1, off);
            q0 += __shfl_down(q0, off); q1 += __shfl_down(q1, off);
            c0 += __shfl_down(c0, off);
            pm = fminf(pm, __shfl_down(pm, off));
            qm = fminf(qm, __shfl_down(qm, off));
        }
        if (tid == 0) {
            PpP[blk * 2 + 0] = p0; PpP[blk * 2 + 1] = p1;
            QqP[blk * 2 + 0] = q0; QqP[blk * 2 + 1] = q1;
            CpP[blk] = c0; pminP[blk] = pm; qminP[blk] = qm;
            if (blk == 0) acc[0] = 0.0f;
        }
    }
}

// ---------------- tile: fp8 gram, 1 tile/block, single barrier ----------------
__global__ __launch_bounds__(256, 2) void tile_kernel(
    const unsigned char* __restrict__ xq, const float* __restrict__ x,
    const int* __restrict__ label, const float* __restrict__ fws,
    float* __restrict__ acc) {
    const float* p = fws + OFF_P;  const float* q = fws + OFF_Q;
    const float* pminP = fws + OFF_PMINP; const float* qminP = fws + OFF_QMINP;

    const int ti = decode_ti(blockIdx.x);
    const int tj = ti + (blockIdx.x - trif(ti));
    const int i0 = ti * 128, j0 = tj * 128;

    // full-K staging: 128 rows x 256 B each, 16-B chunk XOR swizzle
    __shared__ __align__(16) unsigned char As[128 * 256];  // 32 KB
    __shared__ __align__(16) unsigned char Bs[128 * 256];  // 32 KB

    const int tid = threadIdx.x, wave = tid >> 6, lane = tid & 63;
    const int quad = lane >> 4, r = lane & 15;
    const int wm = wave >> 1, wn = wave & 1;

    // staging: instr i covers rows w*32+i*4 .. +3; lane L: row_off=L>>4, phys chunk L&15
    const int rL4 = lane >> 4, c16 = lane & 15;
    {
        const unsigned char* gA = xq + (size_t)(i0 + wave * 32) * D_;
        const unsigned char* gB = xq + (size_t)(j0 + wave * 32) * D_;
        #pragma unroll
        for (int i = 0; i < 8; ++i) {
            const int rr = i * 4 + rL4;                 // row within the wave's 32
            const int key = rr & 7;
            const int srcoff = rr * 256 + ((c16 ^ key) * 16);
            g2l16(gA + srcoff, &As[(wave * 32 + i * 4) * 256]);
            g2l16(gB + srcoff, &Bs[(wave * 32 + i * 4) * 256]);
        }
    }

    // fragment row bases (byte offsets)
    int rbA[4], rbB[4];
    #pragma unroll
    for (int mt = 0; mt < 4; ++mt) rbA[mt] = (wm * 64 + mt * 16 + r) * 256;
    #pragma unroll
    for (int nt = 0; nt < 4; ++nt) rbB[nt] = (wn * 64 + nt * 16 + r) * 256;
    const int q8 = (quad & 1) * 8, qh = quad >> 1, r7 = r & 7;

    floatx4 accv[16];
    #pragma unroll
    for (int t = 0; t < 16; ++t) accv[t] = (floatx4)0.0f;

    __syncthreads();   // the single barrier: drains all 32 g2l16 of this block

    #pragma unroll
    for (int kb = 0; kb < 8; ++kb) {
        const int pcb = (((kb * 2 + qh) ^ r7) * 16) + q8;
        long av[4], bv[4];
        #pragma unroll
        for (int mt = 0; mt < 4; ++mt) av[mt] = *(const long*)(As + rbA[mt] + pcb);
        #pragma unroll
        for (int nt = 0; nt < 4; ++nt) bv[nt] = *(const long*)(Bs + rbB[nt] + pcb);
        #pragma unroll
        for (int mt = 0; mt < 4; ++mt)
            #pragma unroll
            for (int nt = 0; nt < 4; ++nt)
                accv[mt * 4 + nt] = __builtin_amdgcn_mfma_f32_16x16x32_fp8_fp8(
                    av[mt], bv[nt], accv[mt * 4 + nt], 0, 0, 0);
    }

    // ---- epilogue ----
    if (ti != tj) {
        float m = -1e30f;
        #pragma unroll
        for (int t = 0; t < 16; ++t)
            m = fmaxf(m, fmaxf(fmaxf(accv[t][0], accv[t][1]), fmaxf(accv[t][2], accv[t][3])));
        const float pmn = fminf(fminf(pminP[4 * ti], pminP[4 * ti + 1]),
                                fminf(pminP[4 * ti + 2], pminP[4 * ti + 3]));
        const float qmn = fminf(fminf(qminP[4 * tj], qminP[4 * tj + 1]),
                                fminf(qminP[4 * tj + 2], qminP[4 * tj + 3]));
        const float thr = (pmn + qmn + CEPS_ - 1.0f) * 0.5f - 16.0f;  // 16 = fp8 slack
        if (__any(m > thr)) {
            // exact slow path from fp32 x (expected never taken)
            float s = 0.0f;
            #pragma unroll
            for (int mt = 0; mt < 4; ++mt)
                #pragma unroll
                for (int nt = 0; nt < 4; ++nt)
                    #pragma unroll
                    for (int reg = 0; reg < 4; ++reg) {
                        const int gi = i0 + wm * 64 + mt * 16 + quad * 4 + reg;
                        const int gj = j0 + wn * 64 + nt * 16 + r;
                        const float sq8 = p[gi] + q[gj] + CEPS_ - 2.0f * accv[mt * 4 + nt][reg];
                        if (sq8 < 33.0f && label[gi] != label[gj]) {
                            const float* xi = x + (size_t)gi * D_;
                            const float* xj = x + (size_t)gj * D_;
                            float sq = 0.0f;
                            for (int k = 0; k < D_; ++k) {
                                const float df = xi[k] - xj[k] + EPS_;
                                sq += df * df;
                            }
                            if (sq < 1.0f) {
                                const float d = sqrtf(fmaxf(sq, 1e-12f));
                                const float h = MARGIN_ - d;
                                s += h * h;
                            }
                        }
                    }
            #pragma unroll
            for (int off = 32; off; off >>= 1) s += __shfl_down(s, off);
            if (lane == 0) atomicAdd(acc, s);
        }
    } else {
        // diagonal: exact per-pair, strict upper triangle
        float s = 0.0f;
        #pragma unroll
        for (int mt = 0; mt < 4; ++mt)
            #pragma unroll
            for (int nt = 0; nt < 4; ++nt)
                #pragma unroll
                for (int reg = 0; reg < 4; ++reg) {
                    const int il = wm * 64 + mt * 16 + quad * 4 + reg;
                    const int jl = wn * 64 + nt * 16 + r;
                    if (il < jl) {
                        const int gi = i0 + il, gj = j0 + jl;
                        const float sq = p[gi] + q[gj] + CEPS_ - 2.0f * accv[mt * 4 + nt][reg];
                        const float d = sqrtf(fmaxf(sq, 1e-12f));
                        float v;
                        if (label[gi] == label[gj]) v = d * d;
                        else { const float h = fmaxf(MARGIN_ - d, 0.0f); v = h * h; }
                        s += v;
                    }
                }
        #pragma unroll
        for (int off = 32; off; off >>= 1) s += __shfl_down(s, off);
        if (lane == 0) atomicAdd(acc, s);
    }
}

// ---------------- finalize: parallel analytic cross-tile same-label sum ----------------
__global__ __launch_bounds__(256) void finalize_kernel(
    const float* __restrict__ fws, float* __restrict__ out) {
    const float* Tp0 = fws + OFF_TP0; const float* Tp1 = fws + OFF_TP1;
    const float* PpP = fws + OFF_PPP; const float* QqP = fws + OFF_QQP;
    const float* CpP = fws + OFF_CP;
    const float* acc = fws + OFF_ACC;

    __shared__ floatx4 s0q[4][64], s1q[4][64], ssq[4][64];
    __shared__ float g2s;
    __shared__ double tP0[64], tP1[64], tQ0[64], tQ1[64], tC0[64];

    const int tid = threadIdx.x;
    const int quad = tid & 63, tq = tid >> 6;

    floatx4 a0 = (floatx4)0.0f, a1 = (floatx4)0.0f, as = (floatx4)0.0f;
    for (int t = tq; t < 64; t += 4) {
        floatx4 T0 = (floatx4)0.0f, T1 = (floatx4)0.0f;
        #pragma unroll
        for (int b4 = 0; b4 < 4; ++b4) {
            const int blk = 4 * t + b4;
            T0 += *(const floatx4*)&Tp0[blk * 256 + quad * 4];
            T1 += *(const floatx4*)&Tp1[blk * 256 + quad * 4];
        }
        a0 += T0; as += T0 * T0;
        a1 += T1; as += T1 * T1;
    }
    s0q[tq][quad] = a0; s1q[tq][quad] = a1; ssq[tq][quad] = as;

    if (tid >= 64 && tid < 128) {
        const int t = tid - 64;
        double P0 = 0, P1 = 0, Q0 = 0, Q1 = 0, C0 = 0;
        #pragma unroll
        for (int b4 = 0; b4 < 4; ++b4) {
            const int blk = 4 * t + b4;
            P0 += PpP[blk * 2]; P1 += PpP[blk * 2 + 1];
            Q0 += QqP[blk * 2]; Q1 += QqP[blk * 2 + 1];
            C0 += CpP[blk];
        }
        tP0[t] = P0; tP1[t] = P1; tQ0[t] = Q0; tQ1[t] = Q1; tC0[t] = C0;
    }
    __syncthreads();

    if (tid < 64) {
        const floatx4 S0 = s0q[0][tid] + s0q[1][tid] + s0q[2][tid] + s0q[3][tid];
        const floatx4 S1 = s1q[0][tid] + s1q[1][tid] + s1q[2][tid] + s1q[3][tid];
        const floatx4 SS = ssq[0][tid] + ssq[1][tid] + ssq[2][tid] + ssq[3][tid];
        float c = S0[0]*S0[0] + S0[1]*S0[1] + S0[2]*S0[2] + S0[3]*S0[3]
                + S1[0]*S1[0] + S1[1]*S1[1] + S1[2]*S1[2] + S1[3]*S1[3]
                - (SS[0] + SS[1] + SS[2] + SS[3]);
        #pragma unroll
        for (int off = 32; off; off >>= 1) c += __shfl_down(c, off);
        if (tid == 0) g2s = c;
    }
    __syncthreads();

    if (tid == 0) {
        double cross = -(double)g2s;
        double sufC0 = 0, sufC1 = 0, sufQ0 = 0, sufQ1 = 0;
        for (int t = 63; t >= 0; --t) {
            const double C0 = tC0[t], C1 = 128.0 - C0;
            cross += tP0[t] * sufC0 + tP1[t] * sufC1 + sufQ0 * C0 + sufQ1 * C1
                   + (double)CEPS_ * (C0 * sufC0 + C1 * sufC1);
            sufC0 += C0; sufC1 += C1; sufQ0 += tQ0[t]; sufQ1 += tQ1[t];
        }
        const double total = cross + (double)acc[0];
        const double cnt = (double)B_ * (double)(B_ - 1) / 2.0 + 1e-6;
        out[0] = (float)(total / cnt);
    }
}

extern "C" void kernel_launch(void* const* d_in, const int* in_sizes, int n_in,
                              void* d_out, int out_size, void* d_ws, size_t ws_size,
                              hipStream_t stream) {
    const float* x = (const float*)d_in[0];
    const int* label = (const int*)d_in[1];
    float* out = (float*)d_out;

    char* ws = (char*)d_ws;
    unsigned char* xq = (unsigned char*)ws;
    float* fws = (float*)(ws + XBF_BYTES);
    float* acc = fws + OFF_ACC;

    prep_kernel<<<B_ / 32, 256, 0, stream>>>(x, label, xq, fws);
    tile_kernel<<<NTILES_, 256, 0, stream>>>(xq, x, label, fws, acc);
    finalize_kernel<<<1, 256, 0, stream>>>(fws, out);
}